// Round 7
// baseline (455.042 us; speedup 1.0000x reference)
//
#include <hip/hip_runtime.h>
#include <hip/hip_bf16.h>

#define D 1024
#define SLEN 2048
#define BS 16
#define MROWS (BS*SLEN)   // 32768
#define CROWS 64          // chunk rows (M=64: B L2 traffic 1 GB, best measured)
#define NCHUNK (MROWS/CROWS) // 512
#define CPB (SLEN/CROWS)  // 32 chunks per batch

typedef __attribute__((ext_vector_type(8))) short short8;
typedef __attribute__((ext_vector_type(4))) float f32x4;

__device__ __forceinline__ short f2bf(float f) {
  __hip_bfloat16 h = __float2bfloat16(f);
  return __builtin_bit_cast(short, h);
}

// non-temporal float4 load: states is read exactly once (GEMM staging);
// bypass L2 retention so the 2 MB WkT stays L2-resident for the B stream.
__device__ __forceinline__ float4 ntload4(const float* p) {
  f32x4 v = __builtin_nontemporal_load((const f32x4*)p);
  float4 r; r.x = v.x; r.y = v.y; r.z = v.z; r.w = v.w; return r;
}

// ---------------- Kernel 1: Wk (k,n) fp32 -> blocked bf16 WkT ----------------
// WkT[(u*1024 + n)*8 + j] = bf16(Wk[(u*8+j)*1024 + n]), u=0..127.
// Block 0 also zeroes the per-batch split-K counters consumed by energy_gemm
// (same stream -> wk_prep fully precedes energy_gemm).
__global__ __launch_bounds__(256) void wk_prep(const float* __restrict__ Wk,
                                               short* __restrict__ WkT,
                                               int* __restrict__ cnt) {
  const int g = blockIdx.x;        // 0..127
  const int t = threadIdx.x;
  if (g == 0 && t < BS) cnt[t] = 0;
#pragma unroll
  for (int it = 0; it < 4; ++it) {
    const int n = it*256 + t;
    short8 p;
#pragma unroll
    for (int j = 0; j < 8; ++j)
      p[j] = f2bf(Wk[(size_t)(g*8 + j)*D + n]);
    *(short8*)(WkT + ((size_t)g*D + n)*8) = p;
  }
}

// ------- Kernel 2: energy GEMM + fused chunk softmax/attn partial -----------
// R6 config (96us proven): 1024 thr, 16 waves, wave tile 64x64, 4 waves/SIMD.
// New this round:
//  (a) wave-staggered K-start (ks0 = ((w*5)&15)*2, order-independent sum):
//      probe of the convoy theory -- all 16 waves marching through identical
//      {LDS burst, L2 wait, MFMA burst} phases makes pipe demands SUM (80K cyc
//      K-loop vs 37K max component). If phase-lock is real, MfmaUtil rises.
//  (b) split-K-style last-block finalize per batch: the 32nd finishing chunk
//      block of a batch combines the 32 chunk partials (threadfence + atomic
//      counter, device-scope per G12/G16) -- kills the attn_finalize launch.
__global__ __launch_bounds__(1024, 4) void energy_gemm(
    const float* __restrict__ states, const short* __restrict__ WkT,
    const float* __restrict__ bk, const float* __restrict__ We,
    float* __restrict__ eraw, float* __restrict__ pattn,
    float* __restrict__ cmax, float* __restrict__ csum,
    int* __restrict__ cnt,
    float* __restrict__ wts, float* __restrict__ attn)
{
  __shared__ short Al[CROWS * 129 * 8];   // 132 KB: slot(row,u) = row*129 + u
  __shared__ float red2[CROWS * 16];      // 4 KB cross-wave e reduction
  __shared__ float pfin[CROWS];           // p_s = exp(e_s - m_c)
  __shared__ float fstats[2];             // finalize: m_b, 1/S_b
  __shared__ int   lastFlag;

  const int tid  = threadIdx.x;
  const int w    = tid >> 6;        // wave 0..15 -> col group w*64
  const int lane = tid & 63;
  const int quad = lane >> 4;       // k-unit within 32-chunk
  const int l16  = lane & 15;
  const int g    = blockIdx.x;      // chunk id 0..511
  const int m0   = g * CROWS;
  const int b    = g >> 5;          // batch = g / CPB

  // ---- one-time A staging: 64 rows x 1024 k, fp32 -> bf16 (non-temporal) ----
  {
    const int row = tid >> 4;        // 0..63
    const int u0  = tid & 15;
#pragma unroll
    for (int half = 0; half < 2; ++half) {
      const float* Ag = states + (size_t)(m0 + row)*D;
      float4 xs[8];
#pragma unroll
      for (int i = 0; i < 4; ++i) {
        const int u = u0 + (half*4 + i)*16;
        xs[2*i]   = ntload4(Ag + u*8);
        xs[2*i+1] = ntload4(Ag + u*8 + 4);
      }
#pragma unroll
      for (int i = 0; i < 4; ++i) {
        const int u = u0 + (half*4 + i)*16;
        short8 p;
        p[0]=f2bf(xs[2*i].x);   p[1]=f2bf(xs[2*i].y);
        p[2]=f2bf(xs[2*i].z);   p[3]=f2bf(xs[2*i].w);
        p[4]=f2bf(xs[2*i+1].x); p[5]=f2bf(xs[2*i+1].y);
        p[6]=f2bf(xs[2*i+1].z); p[7]=f2bf(xs[2*i+1].w);
        *(short8*)(Al + ((size_t)row*129 + u)*8) = p;
      }
    }
  }
  __syncthreads();

  f32x4 acc[4][4];                  // 64 rows x 64 cols per wave: 64 f32 (AGPR)
#pragma unroll
  for (int mi = 0; mi < 4; ++mi)
#pragma unroll
    for (int ni = 0; ni < 4; ++ni)
      acc[mi][ni] = (f32x4){0.f, 0.f, 0.f, 0.f};

  const short* bbase = WkT + ((size_t)quad*D + w*64 + l16)*8;   // + ks*32768 + ni*128
  const short* abase = Al + ((size_t)l16*129 + quad)*8;         // + mi*16512 + ks*32

  // K-loop: wave-staggered start (wave-uniform ks0; sum over ks is
  // order-independent, so rotation is exact).
  const int ks0 = ((w * 5) & 15) * 2;
#pragma unroll 2
  for (int i = 0; i < 32; ++i) {
    const int ks = (i + ks0) & 31;
    short8 fa[4], fbx[4];
#pragma unroll
    for (int mi = 0; mi < 4; ++mi)
      fa[mi] = *(const short8*)(abase + mi*16512 + ks*32);
    const short* bp = bbase + (size_t)ks*32768;
#pragma unroll
    for (int ni = 0; ni < 4; ++ni)
      fbx[ni] = *(const short8*)(bp + ni*128);
#pragma unroll
    for (int mi = 0; mi < 4; ++mi)
#pragma unroll
      for (int ni = 0; ni < 4; ++ni)
        acc[mi][ni] = __builtin_amdgcn_mfma_f32_16x16x32_bf16(
            fa[mi], fbx[ni], acc[mi][ni], 0, 0, 0);
  }

  // ---- epilogue 1: esum[row] += tanh(relu(c + bk[n])) * We_k[n] ----
  float esum[16];
#pragma unroll
  for (int q = 0; q < 16; ++q) esum[q] = 0.f;
#pragma unroll
  for (int ni = 0; ni < 4; ++ni) {
    const int n = w*64 + ni*16 + l16;
    const float bkv = bk[n];
    const float wev = We[D + n];
#pragma unroll
    for (int mi = 0; mi < 4; ++mi)
#pragma unroll
      for (int r = 0; r < 4; ++r) {
        float x = acc[mi][ni][r] + bkv;
        x = fmaxf(x, 0.f);
        float ex = __expf(2.f * x);
        float th = 1.f - 2.f/(ex + 1.f);
        esum[mi*4 + r] += th * wev;
      }
  }
#pragma unroll
  for (int dd = 1; dd < 16; dd <<= 1)
#pragma unroll
    for (int q = 0; q < 16; ++q)
      esum[q] += __shfl_xor(esum[q], dd, 64);

  if (l16 == 0) {
#pragma unroll
    for (int mi = 0; mi < 4; ++mi)
#pragma unroll
      for (int r = 0; r < 4; ++r)
        red2[(mi*16 + quad*4 + r)*16 + w] = esum[mi*4 + r];
  }
  __syncthreads();

  // ---- epilogue 2: chunk softmax stats (lanes 0..63 = 64 rows) ----
  if (tid < CROWS) {
    float e = 0.f;
#pragma unroll
    for (int wi = 0; wi < 16; ++wi) e += red2[tid*16 + wi];
    eraw[m0 + tid] = e;
    float mm = e;
#pragma unroll
    for (int dd = 1; dd < 64; dd <<= 1) mm = fmaxf(mm, __shfl_xor(mm, dd, 64));
    const float pv = __expf(e - mm);
    float ss = pv;
#pragma unroll
    for (int dd = 1; dd < 64; dd <<= 1) ss += __shfl_xor(ss, dd, 64);
    pfin[tid] = pv;
    if (tid == 0) { cmax[g] = mm; csum[g] = ss; }
  }
  __syncthreads();

  // ---- epilogue 3: partial_d = sum_s p_s * A_lds[s][d], d = 2*t, 2*t+1 ----
  if (tid < 512) {
    const int u    = tid >> 2;          // d/8
    const int joff = (tid & 3) * 2;     // d%8
    const short* ap = Al + (size_t)u*8 + joff;
    float a0 = 0.f, a1 = 0.f;
#pragma unroll 16
    for (int row = 0; row < CROWS; ++row) {
      const unsigned int bits = *(const unsigned int*)(ap + (size_t)row*1032);
      const float pv = pfin[row];
      const float lo = __builtin_bit_cast(float, bits << 16);
      const float hi = __builtin_bit_cast(float, bits & 0xffff0000u);
      a0 = fmaf(pv, lo, a0);
      a1 = fmaf(pv, hi, a1);
    }
    float2 o; o.x = a0; o.y = a1;
    *(float2*)(pattn + (size_t)g*D + 2*tid) = o;
  }

  // ---- split-K completion: last chunk block of this batch finalizes --------
  __threadfence();                  // release this block's stores (device scope)
  __syncthreads();
  if (tid == 0) {
    const int old = atomicAdd(&cnt[b], 1);
    lastFlag = (old == CPB - 1);
  }
  __syncthreads();
  if (!lastFlag) return;
  __threadfence();                  // acquire: see all 32 chunks' stores

  // stats over the batch's 32 chunks (lanes 0..31 of wave 0)
  if (tid < CPB) {
    const float m = cmax[b*CPB + tid];
    float mm = m;
#pragma unroll
    for (int dd = 1; dd < CPB; dd <<= 1) mm = fmaxf(mm, __shfl_xor(mm, dd, 64));
    const float e = __expf(m - mm);
    red2[tid] = e;                  // chunk rescale factors
    float s = e * csum[b*CPB + tid];
#pragma unroll
    for (int dd = 1; dd < CPB; dd <<= 1) s += __shfl_xor(s, dd, 64);
    if (tid == 0) { fstats[0] = mm; fstats[1] = 1.f / s; }
  }
  __syncthreads();
  const float m_b = fstats[0];
  const float inv = fstats[1];

  // weights: 2048 per batch, 2 per thread
#pragma unroll
  for (int j = 0; j < 2; ++j) {
    const int s = j*1024 + tid;
    wts[(size_t)b*SLEN + s] = __expf(eraw[(size_t)b*SLEN + s] - m_b) * inv;
  }

  // attn: 1024 cols, 1 per thread, combine 32 chunks
  {
    float a = 0.f;
#pragma unroll
    for (int c = 0; c < CPB; ++c)
      a = fmaf(red2[c], pattn[((size_t)(b*CPB + c))*D + tid], a);
    attn[(size_t)b*D + tid] = a * inv;
  }
}

extern "C" void kernel_launch(void* const* d_in, const int* in_sizes, int n_in,
                              void* d_out, int out_size, void* d_ws, size_t ws_size,
                              hipStream_t stream) {
  // inputs: 0=query 1=states 2=Wq 3=bq 4=Wk 5=bk 6=We 7=be
  // q-path terms are constant per softmax row -> cancel; dead code.
  const float* states = (const float*)d_in[1];
  const float* Wk     = (const float*)d_in[4];
  const float* bk     = (const float*)d_in[5];
  const float* We     = (const float*)d_in[6];
  float* out = (float*)d_out;            // [0:32768) attn_weights, [32768:49152) attn

  char* ws = (char*)d_ws;
  short* WkT   = (short*)ws;  ws += (size_t)D*D*sizeof(short);        // 2 MB
  float* eraw  = (float*)ws;  ws += (size_t)MROWS*sizeof(float);      // 128 KB
  float* pattn = (float*)ws;  ws += (size_t)NCHUNK*D*sizeof(float);   // 2 MB
  float* cmaxp = (float*)ws;  ws += (size_t)NCHUNK*sizeof(float);
  float* csump = (float*)ws;  ws += (size_t)NCHUNK*sizeof(float);
  int*   cnt   = (int*)ws;

  (void)in_sizes; (void)n_in; (void)out_size; (void)ws_size;

  wk_prep<<<128, 256, 0, stream>>>(Wk, WkT, cnt);
  energy_gemm<<<NCHUNK, 1024, 0, stream>>>(states, WkT, bk, We, eraw, pattn,
                                           cmaxp, csump, cnt,
                                           out, out + MROWS);
}

// Round 8
// 451.285 us; speedup vs baseline: 1.0083x; 1.0083x over previous
//
#include <hip/hip_runtime.h>
#include <hip/hip_bf16.h>

#define D 1024
#define SLEN 2048
#define BS 16
#define MROWS (BS*SLEN)   // 32768
#define CROWS 64          // chunk rows (M=64: B L2 traffic 1 GB, best measured)
#define NCHUNK (MROWS/CROWS) // 512
#define CPB (SLEN/CROWS)  // 32 chunks per batch

typedef __attribute__((ext_vector_type(8))) short short8;
typedef __attribute__((ext_vector_type(4))) float f32x4;

__device__ __forceinline__ short f2bf(float f) {
  __hip_bfloat16 h = __float2bfloat16(f);
  return __builtin_bit_cast(short, h);
}

// non-temporal float4 load: states is read exactly once (GEMM staging);
// bypass L2 retention so the 2 MB WkT stays L2-resident for the B stream.
__device__ __forceinline__ float4 ntload4(const float* p) {
  f32x4 v = __builtin_nontemporal_load((const f32x4*)p);
  float4 r; r.x = v.x; r.y = v.y; r.z = v.z; r.w = v.w; return r;
}

// ---------------- Kernel 1: Wk (k,n) fp32 -> blocked bf16 WkT ----------------
// WkT[(u*1024 + n)*8 + j] = bf16(Wk[(u*8+j)*1024 + n]), u=0..127.
// Block 0 also zeroes the per-batch split-K counters consumed by energy_gemm
// (same stream -> wk_prep fully precedes energy_gemm).
__global__ __launch_bounds__(256) void wk_prep(const float* __restrict__ Wk,
                                               short* __restrict__ WkT,
                                               int* __restrict__ cnt) {
  const int g = blockIdx.x;        // 0..127
  const int t = threadIdx.x;
  if (g == 0 && t < BS) cnt[t] = 0;
#pragma unroll
  for (int it = 0; it < 4; ++it) {
    const int n = it*256 + t;
    short8 p;
#pragma unroll
    for (int j = 0; j < 8; ++j)
      p[j] = f2bf(Wk[(size_t)(g*8 + j)*D + n]);
    *(short8*)(WkT + ((size_t)g*D + n)*8) = p;
  }
}

// ------- Kernel 2: energy GEMM + fused chunk softmax/attn partial -----------
// R6 config (96us proven): 1024 thr, 16 waves, wave tile 64x64, 4 waves/SIMD,
// SEQUENTIAL affine K-loop (R7 lesson: the staggered `(i+ks0)&31` index broke
// the compiler's affine address induction -> 3x slowdown, MfmaUtil 9.5%,
// everything stalled on per-iteration address calc + waitcnt. Never make the
// hot-loop index non-affine).
// Split-K last-block finalize kept from R7 (validated: non-GEMM 171->158us,
// correctness clean): 32nd finishing chunk of a batch combines the partials.
__global__ __launch_bounds__(1024, 4) void energy_gemm(
    const float* __restrict__ states, const short* __restrict__ WkT,
    const float* __restrict__ bk, const float* __restrict__ We,
    float* __restrict__ eraw, float* __restrict__ pattn,
    float* __restrict__ cmax, float* __restrict__ csum,
    int* __restrict__ cnt,
    float* __restrict__ wts, float* __restrict__ attn)
{
  __shared__ short Al[CROWS * 129 * 8];   // 132 KB: slot(row,u) = row*129 + u
  __shared__ float red2[CROWS * 16];      // 4 KB cross-wave e reduction
  __shared__ float pfin[CROWS];           // p_s = exp(e_s - m_c)
  __shared__ float fstats[2];             // finalize: m_b, 1/S_b
  __shared__ int   lastFlag;

  const int tid  = threadIdx.x;
  const int w    = tid >> 6;        // wave 0..15 -> col group w*64
  const int lane = tid & 63;
  const int quad = lane >> 4;       // k-unit within 32-chunk
  const int l16  = lane & 15;
  const int g    = blockIdx.x;      // chunk id 0..511
  const int m0   = g * CROWS;
  const int b    = g >> 5;          // batch = g / CPB

  // ---- one-time A staging: 64 rows x 1024 k, fp32 -> bf16 (non-temporal) ----
  {
    const int row = tid >> 4;        // 0..63
    const int u0  = tid & 15;
#pragma unroll
    for (int half = 0; half < 2; ++half) {
      const float* Ag = states + (size_t)(m0 + row)*D;
      float4 xs[8];
#pragma unroll
      for (int i = 0; i < 4; ++i) {
        const int u = u0 + (half*4 + i)*16;
        xs[2*i]   = ntload4(Ag + u*8);
        xs[2*i+1] = ntload4(Ag + u*8 + 4);
      }
#pragma unroll
      for (int i = 0; i < 4; ++i) {
        const int u = u0 + (half*4 + i)*16;
        short8 p;
        p[0]=f2bf(xs[2*i].x);   p[1]=f2bf(xs[2*i].y);
        p[2]=f2bf(xs[2*i].z);   p[3]=f2bf(xs[2*i].w);
        p[4]=f2bf(xs[2*i+1].x); p[5]=f2bf(xs[2*i+1].y);
        p[6]=f2bf(xs[2*i+1].z); p[7]=f2bf(xs[2*i+1].w);
        *(short8*)(Al + ((size_t)row*129 + u)*8) = p;
      }
    }
  }
  __syncthreads();

  f32x4 acc[4][4];                  // 64 rows x 64 cols per wave: 64 f32 (AGPR)
#pragma unroll
  for (int mi = 0; mi < 4; ++mi)
#pragma unroll
    for (int ni = 0; ni < 4; ++ni)
      acc[mi][ni] = (f32x4){0.f, 0.f, 0.f, 0.f};

  const short* bbase = WkT + ((size_t)quad*D + w*64 + l16)*8;   // + ks*32768 + ni*128
  const short* abase = Al + ((size_t)l16*129 + quad)*8;         // + mi*16512 + ks*32

  // K-loop: sequential, affine, single-buffered fragments; latency hidden by
  // 4 waves/SIMD TLP (R6's proven 96us form).
#pragma unroll 2
  for (int ks = 0; ks < 32; ++ks) {
    short8 fa[4], fbx[4];
#pragma unroll
    for (int mi = 0; mi < 4; ++mi)
      fa[mi] = *(const short8*)(abase + mi*16512 + ks*32);
    const short* bp = bbase + (size_t)ks*32768;
#pragma unroll
    for (int ni = 0; ni < 4; ++ni)
      fbx[ni] = *(const short8*)(bp + ni*128);
#pragma unroll
    for (int mi = 0; mi < 4; ++mi)
#pragma unroll
      for (int ni = 0; ni < 4; ++ni)
        acc[mi][ni] = __builtin_amdgcn_mfma_f32_16x16x32_bf16(
            fa[mi], fbx[ni], acc[mi][ni], 0, 0, 0);
  }

  // ---- epilogue 1: esum[row] += tanh(relu(c + bk[n])) * We_k[n] ----
  float esum[16];
#pragma unroll
  for (int q = 0; q < 16; ++q) esum[q] = 0.f;
#pragma unroll
  for (int ni = 0; ni < 4; ++ni) {
    const int n = w*64 + ni*16 + l16;
    const float bkv = bk[n];
    const float wev = We[D + n];
#pragma unroll
    for (int mi = 0; mi < 4; ++mi)
#pragma unroll
      for (int r = 0; r < 4; ++r) {
        float x = acc[mi][ni][r] + bkv;
        x = fmaxf(x, 0.f);
        float ex = __expf(2.f * x);
        float th = 1.f - 2.f/(ex + 1.f);
        esum[mi*4 + r] += th * wev;
      }
  }
#pragma unroll
  for (int dd = 1; dd < 16; dd <<= 1)
#pragma unroll
    for (int q = 0; q < 16; ++q)
      esum[q] += __shfl_xor(esum[q], dd, 64);

  if (l16 == 0) {
#pragma unroll
    for (int mi = 0; mi < 4; ++mi)
#pragma unroll
      for (int r = 0; r < 4; ++r)
        red2[(mi*16 + quad*4 + r)*16 + w] = esum[mi*4 + r];
  }
  __syncthreads();

  // ---- epilogue 2: chunk softmax stats (lanes 0..63 = 64 rows) ----
  if (tid < CROWS) {
    float e = 0.f;
#pragma unroll
    for (int wi = 0; wi < 16; ++wi) e += red2[tid*16 + wi];
    eraw[m0 + tid] = e;
    float mm = e;
#pragma unroll
    for (int dd = 1; dd < 64; dd <<= 1) mm = fmaxf(mm, __shfl_xor(mm, dd, 64));
    const float pv = __expf(e - mm);
    float ss = pv;
#pragma unroll
    for (int dd = 1; dd < 64; dd <<= 1) ss += __shfl_xor(ss, dd, 64);
    pfin[tid] = pv;
    if (tid == 0) { cmax[g] = mm; csum[g] = ss; }
  }
  __syncthreads();

  // ---- epilogue 3: partial_d = sum_s p_s * A_lds[s][d], d = 2*t, 2*t+1 ----
  if (tid < 512) {
    const int u    = tid >> 2;          // d/8
    const int joff = (tid & 3) * 2;     // d%8
    const short* ap = Al + (size_t)u*8 + joff;
    float a0 = 0.f, a1 = 0.f;
#pragma unroll 16
    for (int row = 0; row < CROWS; ++row) {
      const unsigned int bits = *(const unsigned int*)(ap + (size_t)row*1032);
      const float pv = pfin[row];
      const float lo = __builtin_bit_cast(float, bits << 16);
      const float hi = __builtin_bit_cast(float, bits & 0xffff0000u);
      a0 = fmaf(pv, lo, a0);
      a1 = fmaf(pv, hi, a1);
    }
    float2 o; o.x = a0; o.y = a1;
    *(float2*)(pattn + (size_t)g*D + 2*tid) = o;
  }

  // ---- split-K completion: last chunk block of this batch finalizes --------
  __threadfence();                  // release this block's stores (device scope)
  __syncthreads();
  if (tid == 0) {
    const int old = atomicAdd(&cnt[b], 1);
    lastFlag = (old == CPB - 1);
  }
  __syncthreads();
  if (!lastFlag) return;
  __threadfence();                  // acquire: see all 32 chunks' stores

  // stats over the batch's 32 chunks (lanes 0..31 of wave 0)
  if (tid < CPB) {
    const float m = cmax[b*CPB + tid];
    float mm = m;
#pragma unroll
    for (int dd = 1; dd < CPB; dd <<= 1) mm = fmaxf(mm, __shfl_xor(mm, dd, 64));
    const float e = __expf(m - mm);
    red2[tid] = e;                  // chunk rescale factors
    float s = e * csum[b*CPB + tid];
#pragma unroll
    for (int dd = 1; dd < CPB; dd <<= 1) s += __shfl_xor(s, dd, 64);
    if (tid == 0) { fstats[0] = mm; fstats[1] = 1.f / s; }
  }
  __syncthreads();
  const float m_b = fstats[0];
  const float inv = fstats[1];

  // weights: 2048 per batch, 2 per thread
#pragma unroll
  for (int j = 0; j < 2; ++j) {
    const int s = j*1024 + tid;
    wts[(size_t)b*SLEN + s] = __expf(eraw[(size_t)b*SLEN + s] - m_b) * inv;
  }

  // attn: 1024 cols, 1 per thread, combine 32 chunks
  {
    float a = 0.f;
#pragma unroll
    for (int c = 0; c < CPB; ++c)
      a = fmaf(red2[c], pattn[((size_t)(b*CPB + c))*D + tid], a);
    attn[(size_t)b*D + tid] = a * inv;
  }
}

extern "C" void kernel_launch(void* const* d_in, const int* in_sizes, int n_in,
                              void* d_out, int out_size, void* d_ws, size_t ws_size,
                              hipStream_t stream) {
  // inputs: 0=query 1=states 2=Wq 3=bq 4=Wk 5=bk 6=We 7=be
  // q-path terms are constant per softmax row -> cancel; dead code.
  const float* states = (const float*)d_in[1];
  const float* Wk     = (const float*)d_in[4];
  const float* bk     = (const float*)d_in[5];
  const float* We     = (const float*)d_in[6];
  float* out = (float*)d_out;            // [0:32768) attn_weights, [32768:49152) attn

  char* ws = (char*)d_ws;
  short* WkT   = (short*)ws;  ws += (size_t)D*D*sizeof(short);        // 2 MB
  float* eraw  = (float*)ws;  ws += (size_t)MROWS*sizeof(float);      // 128 KB
  float* pattn = (float*)ws;  ws += (size_t)NCHUNK*D*sizeof(float);   // 2 MB
  float* cmaxp = (float*)ws;  ws += (size_t)NCHUNK*sizeof(float);
  float* csump = (float*)ws;  ws += (size_t)NCHUNK*sizeof(float);
  int*   cnt   = (int*)ws;

  (void)in_sizes; (void)n_in; (void)out_size; (void)ws_size;

  wk_prep<<<128, 256, 0, stream>>>(Wk, WkT, cnt);
  energy_gemm<<<NCHUNK, 1024, 0, stream>>>(states, WkT, bk, We, eraw, pattn,
                                           cmaxp, csump, cnt,
                                           out, out + MROWS);
}

// Round 9
// 270.410 us; speedup vs baseline: 1.6828x; 1.6689x over previous
//
#include <hip/hip_runtime.h>
#include <hip/hip_bf16.h>

#define D 1024
#define SLEN 2048
#define BS 16
#define MROWS (BS*SLEN)   // 32768
#define CROWS 64          // chunk rows (M=64: B L2 traffic 1 GB, best measured)
#define NCHUNK (MROWS/CROWS) // 512
#define CPB (SLEN/CROWS)  // 32 chunks per batch

typedef __attribute__((ext_vector_type(8))) short short8;
typedef __attribute__((ext_vector_type(4))) float f32x4;

__device__ __forceinline__ short f2bf(float f) {
  __hip_bfloat16 h = __float2bfloat16(f);
  return __builtin_bit_cast(short, h);
}

// non-temporal float4 load: states is read exactly once (GEMM staging);
// bypass L2 retention so the 2 MB WkT stays L2-resident for the B stream.
__device__ __forceinline__ float4 ntload4(const float* p) {
  f32x4 v = __builtin_nontemporal_load((const f32x4*)p);
  float4 r; r.x = v.x; r.y = v.y; r.z = v.z; r.w = v.w; return r;
}

// ---------------- Kernel 1: Wk (k,n) fp32 -> blocked bf16 WkT ----------------
// WkT[(u*1024 + n)*8 + j] = bf16(Wk[(u*8+j)*1024 + n]), u=0..127.
__global__ __launch_bounds__(256) void wk_prep(const float* __restrict__ Wk,
                                               short* __restrict__ WkT) {
  const int g = blockIdx.x;        // 0..127
  const int t = threadIdx.x;
#pragma unroll
  for (int it = 0; it < 4; ++it) {
    const int n = it*256 + t;
    short8 p;
#pragma unroll
    for (int j = 0; j < 8; ++j)
      p[j] = f2bf(Wk[(size_t)(g*8 + j)*D + n]);
    *(short8*)(WkT + ((size_t)g*D + n)*8) = p;
  }
}

// ------- Kernel 2: energy GEMM + fused chunk softmax/attn partial -----------
// R6's proven 96us config: 1024 thr, 16 waves, wave tile 64x64, 4 waves/SIMD,
// sequential affine K-loop, NO device fences (R7/R8 lesson: per-block
// __threadfence costs ~95us/block in L2-writeback stalls -> never fence the
// hot kernel; split-K/grid-sync launch merging is poison on gfx950).
__global__ __launch_bounds__(1024, 4) void energy_gemm(
    const float* __restrict__ states, const short* __restrict__ WkT,
    const float* __restrict__ bk, const float* __restrict__ We,
    float* __restrict__ eraw, float* __restrict__ pattn,
    float* __restrict__ cmax, float* __restrict__ csum)
{
  __shared__ short Al[CROWS * 129 * 8];   // 132 KB: slot(row,u) = row*129 + u
  __shared__ float red2[CROWS * 16];      // 4 KB cross-wave e reduction
  __shared__ float pfin[CROWS];           // p_s = exp(e_s - m_c)

  const int tid  = threadIdx.x;
  const int w    = tid >> 6;        // wave 0..15 -> col group w*64
  const int lane = tid & 63;
  const int quad = lane >> 4;       // k-unit within 32-chunk
  const int l16  = lane & 15;
  const int g    = blockIdx.x;      // chunk id 0..511
  const int m0   = g * CROWS;

  // ---- one-time A staging: 64 rows x 1024 k, fp32 -> bf16 (non-temporal) ----
  {
    const int row = tid >> 4;        // 0..63
    const int u0  = tid & 15;
#pragma unroll
    for (int half = 0; half < 2; ++half) {
      const float* Ag = states + (size_t)(m0 + row)*D;
      float4 xs[8];
#pragma unroll
      for (int i = 0; i < 4; ++i) {
        const int u = u0 + (half*4 + i)*16;
        xs[2*i]   = ntload4(Ag + u*8);
        xs[2*i+1] = ntload4(Ag + u*8 + 4);
      }
#pragma unroll
      for (int i = 0; i < 4; ++i) {
        const int u = u0 + (half*4 + i)*16;
        short8 p;
        p[0]=f2bf(xs[2*i].x);   p[1]=f2bf(xs[2*i].y);
        p[2]=f2bf(xs[2*i].z);   p[3]=f2bf(xs[2*i].w);
        p[4]=f2bf(xs[2*i+1].x); p[5]=f2bf(xs[2*i+1].y);
        p[6]=f2bf(xs[2*i+1].z); p[7]=f2bf(xs[2*i+1].w);
        *(short8*)(Al + ((size_t)row*129 + u)*8) = p;
      }
    }
  }
  __syncthreads();

  f32x4 acc[4][4];                  // 64 rows x 64 cols per wave: 64 f32 (AGPR)
#pragma unroll
  for (int mi = 0; mi < 4; ++mi)
#pragma unroll
    for (int ni = 0; ni < 4; ++ni)
      acc[mi][ni] = (f32x4){0.f, 0.f, 0.f, 0.f};

  const short* bbase = WkT + ((size_t)quad*D + w*64 + l16)*8;   // + ks*32768 + ni*128
  const short* abase = Al + ((size_t)l16*129 + quad)*8;         // + mi*16512 + ks*32

  // K-loop: sequential, affine, single-buffered fragments; latency hidden by
  // 4 waves/SIMD TLP. B (global/L2) loads issued BEFORE the A ds_reads so
  // the L2 round-trip flies under the LDS reads.
#pragma unroll 2
  for (int ks = 0; ks < 32; ++ks) {
    short8 fa[4], fbx[4];
    const short* bp = bbase + (size_t)ks*32768;
#pragma unroll
    for (int ni = 0; ni < 4; ++ni)
      fbx[ni] = *(const short8*)(bp + ni*128);
#pragma unroll
    for (int mi = 0; mi < 4; ++mi)
      fa[mi] = *(const short8*)(abase + mi*16512 + ks*32);
#pragma unroll
    for (int mi = 0; mi < 4; ++mi)
#pragma unroll
      for (int ni = 0; ni < 4; ++ni)
        acc[mi][ni] = __builtin_amdgcn_mfma_f32_16x16x32_bf16(
            fa[mi], fbx[ni], acc[mi][ni], 0, 0, 0);
  }

  // ---- epilogue 1: esum[row] += tanh(relu(c + bk[n])) * We_k[n] ----
  float esum[16];
#pragma unroll
  for (int q = 0; q < 16; ++q) esum[q] = 0.f;
#pragma unroll
  for (int ni = 0; ni < 4; ++ni) {
    const int n = w*64 + ni*16 + l16;
    const float bkv = bk[n];
    const float wev = We[D + n];
#pragma unroll
    for (int mi = 0; mi < 4; ++mi)
#pragma unroll
      for (int r = 0; r < 4; ++r) {
        float x = acc[mi][ni][r] + bkv;
        x = fmaxf(x, 0.f);
        float ex = __expf(2.f * x);
        float th = 1.f - 2.f/(ex + 1.f);
        esum[mi*4 + r] += th * wev;
      }
  }
#pragma unroll
  for (int dd = 1; dd < 16; dd <<= 1)
#pragma unroll
    for (int q = 0; q < 16; ++q)
      esum[q] += __shfl_xor(esum[q], dd, 64);

  if (l16 == 0) {
#pragma unroll
    for (int mi = 0; mi < 4; ++mi)
#pragma unroll
      for (int r = 0; r < 4; ++r)
        red2[(mi*16 + quad*4 + r)*16 + w] = esum[mi*4 + r];
  }
  __syncthreads();

  // ---- epilogue 2: chunk softmax stats (lanes 0..63 = 64 rows) ----
  if (tid < CROWS) {
    float e = 0.f;
#pragma unroll
    for (int wi = 0; wi < 16; ++wi) e += red2[tid*16 + wi];
    eraw[m0 + tid] = e;
    float mm = e;
#pragma unroll
    for (int dd = 1; dd < 64; dd <<= 1) mm = fmaxf(mm, __shfl_xor(mm, dd, 64));
    const float pv = __expf(e - mm);
    float ss = pv;
#pragma unroll
    for (int dd = 1; dd < 64; dd <<= 1) ss += __shfl_xor(ss, dd, 64);
    pfin[tid] = pv;
    if (tid == 0) { cmax[g] = mm; csum[g] = ss; }
  }
  __syncthreads();

  // ---- epilogue 3: partial_d = sum_s p_s * A_lds[s][d], d = 2*t, 2*t+1 ----
  if (tid < 512) {
    const int u    = tid >> 2;          // d/8
    const int joff = (tid & 3) * 2;     // d%8
    const short* ap = Al + (size_t)u*8 + joff;
    float a0 = 0.f, a1 = 0.f;
#pragma unroll 16
    for (int row = 0; row < CROWS; ++row) {
      const unsigned int bits = *(const unsigned int*)(ap + (size_t)row*1032);
      const float pv = pfin[row];
      const float lo = __builtin_bit_cast(float, bits << 16);
      const float hi = __builtin_bit_cast(float, bits & 0xffff0000u);
      a0 = fmaf(pv, lo, a0);
      a1 = fmaf(pv, hi, a1);
    }
    float2 o; o.x = a0; o.y = a1;
    *(float2*)(pattn + (size_t)g*D + 2*tid) = o;
  }
}

// ---------- Kernel 3: combine 32 chunk-partials per batch (tiny) ------------
// m_b = max_c m_c ; S_b = sum_c exp(m_c-m_b)*sumexp_c ;
// wts = exp(e-m_b)/S_b ; attn = (sum_c exp(m_c-m_b)*partial_c)/S_b.
__global__ __launch_bounds__(512) void attn_finalize(
    const float* __restrict__ eraw, const float* __restrict__ pattn,
    const float* __restrict__ cmax, const float* __restrict__ csum,
    float* __restrict__ wts, float* __restrict__ attn)
{
  const int b = blockIdx.x;
  const int t = threadIdx.x;
  __shared__ float scl[CPB];
  __shared__ float stats[2];

  if (t < CPB) {
    const float m = cmax[b*CPB + t];
    float mm = m;
#pragma unroll
    for (int dd = 1; dd < CPB; dd <<= 1) mm = fmaxf(mm, __shfl_xor(mm, dd, 64));
    const float e = __expf(m - mm);
    scl[t] = e;
    float s = e * csum[b*CPB + t];
#pragma unroll
    for (int dd = 1; dd < CPB; dd <<= 1) s += __shfl_xor(s, dd, 64);
    if (t == 0) { stats[0] = mm; stats[1] = 1.f / s; }
  }
  __syncthreads();
  const float m_b = stats[0];
  const float inv = stats[1];

  // weights: 2048 per batch, 4 per thread
#pragma unroll
  for (int j = 0; j < 4; ++j) {
    const int s = j*512 + t;
    wts[(size_t)b*SLEN + s] = __expf(eraw[(size_t)b*SLEN + s] - m_b) * inv;
  }

  // attn: 1024 cols, 2 per thread, combine CPB chunks
  float a0 = 0.f, a1 = 0.f;
#pragma unroll
  for (int c = 0; c < CPB; ++c) {
    const float sc = scl[c];
    const float* pp = pattn + ((size_t)(b*CPB + c))*D + t;
    a0 = fmaf(sc, pp[0],   a0);
    a1 = fmaf(sc, pp[512], a1);
  }
  attn[(size_t)b*D + t]       = a0 * inv;
  attn[(size_t)b*D + 512 + t] = a1 * inv;
}

extern "C" void kernel_launch(void* const* d_in, const int* in_sizes, int n_in,
                              void* d_out, int out_size, void* d_ws, size_t ws_size,
                              hipStream_t stream) {
  // inputs: 0=query 1=states 2=Wq 3=bq 4=Wk 5=bk 6=We 7=be
  // q-path terms are constant per softmax row -> cancel; dead code.
  const float* states = (const float*)d_in[1];
  const float* Wk     = (const float*)d_in[4];
  const float* bk     = (const float*)d_in[5];
  const float* We     = (const float*)d_in[6];
  float* out = (float*)d_out;            // [0:32768) attn_weights, [32768:49152) attn

  char* ws = (char*)d_ws;
  short* WkT   = (short*)ws;  ws += (size_t)D*D*sizeof(short);        // 2 MB
  float* eraw  = (float*)ws;  ws += (size_t)MROWS*sizeof(float);      // 128 KB
  float* pattn = (float*)ws;  ws += (size_t)NCHUNK*D*sizeof(float);   // 2 MB
  float* cmaxp = (float*)ws;  ws += (size_t)NCHUNK*sizeof(float);
  float* csump = (float*)ws;

  (void)in_sizes; (void)n_in; (void)out_size; (void)ws_size;

  wk_prep<<<128, 256, 0, stream>>>(Wk, WkT);
  energy_gemm<<<NCHUNK, 1024, 0, stream>>>(states, WkT, bk, We, eraw, pattn,
                                           cmaxp, csump);
  attn_finalize<<<BS, 512, 0, stream>>>(eraw, pattn, cmaxp, csump, out, out + MROWS);
}

// Round 10
// 267.802 us; speedup vs baseline: 1.6992x; 1.0097x over previous
//
#include <hip/hip_runtime.h>
#include <hip/hip_bf16.h>

#define D 1024
#define SLEN 2048
#define BS 16
#define MROWS (BS*SLEN)   // 32768
#define CROWS 64          // chunk rows (M=64: B L2 traffic 1 GB, best measured)
#define NCHUNK (MROWS/CROWS) // 512
#define CPB (SLEN/CROWS)  // 32 chunks per batch

typedef __attribute__((ext_vector_type(8))) short short8;
typedef __attribute__((ext_vector_type(4))) float f32x4;

__device__ __forceinline__ short f2bf(float f) {
  __hip_bfloat16 h = __float2bfloat16(f);
  return __builtin_bit_cast(short, h);
}

// non-temporal float4 load: states is read exactly once (GEMM staging);
// bypass L2 retention so the 2 MB WkT stays L2-resident for the B stream.
__device__ __forceinline__ float4 ntload4(const float* p) {
  f32x4 v = __builtin_nontemporal_load((const f32x4*)p);
  float4 r; r.x = v.x; r.y = v.y; r.z = v.z; r.w = v.w; return r;
}

// ---------------- Kernel 1: Wk (k,n) fp32 -> blocked bf16 WkT ----------------
// WkT[(u*1024 + n)*8 + j] = bf16(Wk[(u*8+j)*1024 + n]), u=0..127.
__global__ __launch_bounds__(256) void wk_prep(const float* __restrict__ Wk,
                                               short* __restrict__ WkT) {
  const int g = blockIdx.x;        // 0..127
  const int t = threadIdx.x;
#pragma unroll
  for (int it = 0; it < 4; ++it) {
    const int n = it*256 + t;
    short8 p;
#pragma unroll
    for (int j = 0; j < 8; ++j)
      p[j] = f2bf(Wk[(size_t)(g*8 + j)*D + n]);
    *(short8*)(WkT + ((size_t)g*D + n)*8) = p;
  }
}

// ------- Kernel 2: energy GEMM + fused chunk softmax/attn partial -----------
// R6's proven 96us config: 1024 thr, 16 waves, wave tile 64x64, 4 waves/SIMD,
// sequential affine K-loop, A ds_reads BEFORE B loads (R9 lesson: swapping
// that order cost +3.5us -- the schedule is compiler-fragile, keep the
// measured form). NO device fences (R7/R8: per-block __threadfence costs
// ~95us/block in L2-writeback stalls).
// Single change this round: unroll 2 -> 4 (VGPR 52 of 128 cap -> headroom
// for two extra ksteps' B loads in flight; spill watch: WRITE_SIZE).
__global__ __launch_bounds__(1024, 4) void energy_gemm(
    const float* __restrict__ states, const short* __restrict__ WkT,
    const float* __restrict__ bk, const float* __restrict__ We,
    float* __restrict__ eraw, float* __restrict__ pattn,
    float* __restrict__ cmax, float* __restrict__ csum)
{
  __shared__ short Al[CROWS * 129 * 8];   // 132 KB: slot(row,u) = row*129 + u
  __shared__ float red2[CROWS * 16];      // 4 KB cross-wave e reduction
  __shared__ float pfin[CROWS];           // p_s = exp(e_s - m_c)

  const int tid  = threadIdx.x;
  const int w    = tid >> 6;        // wave 0..15 -> col group w*64
  const int lane = tid & 63;
  const int quad = lane >> 4;       // k-unit within 32-chunk
  const int l16  = lane & 15;
  const int g    = blockIdx.x;      // chunk id 0..511
  const int m0   = g * CROWS;

  // ---- one-time A staging: 64 rows x 1024 k, fp32 -> bf16 (non-temporal) ----
  {
    const int row = tid >> 4;        // 0..63
    const int u0  = tid & 15;
#pragma unroll
    for (int half = 0; half < 2; ++half) {
      const float* Ag = states + (size_t)(m0 + row)*D;
      float4 xs[8];
#pragma unroll
      for (int i = 0; i < 4; ++i) {
        const int u = u0 + (half*4 + i)*16;
        xs[2*i]   = ntload4(Ag + u*8);
        xs[2*i+1] = ntload4(Ag + u*8 + 4);
      }
#pragma unroll
      for (int i = 0; i < 4; ++i) {
        const int u = u0 + (half*4 + i)*16;
        short8 p;
        p[0]=f2bf(xs[2*i].x);   p[1]=f2bf(xs[2*i].y);
        p[2]=f2bf(xs[2*i].z);   p[3]=f2bf(xs[2*i].w);
        p[4]=f2bf(xs[2*i+1].x); p[5]=f2bf(xs[2*i+1].y);
        p[6]=f2bf(xs[2*i+1].z); p[7]=f2bf(xs[2*i+1].w);
        *(short8*)(Al + ((size_t)row*129 + u)*8) = p;
      }
    }
  }
  __syncthreads();

  f32x4 acc[4][4];                  // 64 rows x 64 cols per wave: 64 f32 (AGPR)
#pragma unroll
  for (int mi = 0; mi < 4; ++mi)
#pragma unroll
    for (int ni = 0; ni < 4; ++ni)
      acc[mi][ni] = (f32x4){0.f, 0.f, 0.f, 0.f};

  const short* bbase = WkT + ((size_t)quad*D + w*64 + l16)*8;   // + ks*32768 + ni*128
  const short* abase = Al + ((size_t)l16*129 + quad)*8;         // + mi*16512 + ks*32

  // K-loop: sequential, affine, single-buffered fragments; latency hidden by
  // 4 waves/SIMD TLP. Order: A ds_reads, then B loads, then MFMA (R6 form).
#pragma unroll 4
  for (int ks = 0; ks < 32; ++ks) {
    short8 fa[4], fbx[4];
#pragma unroll
    for (int mi = 0; mi < 4; ++mi)
      fa[mi] = *(const short8*)(abase + mi*16512 + ks*32);
    const short* bp = bbase + (size_t)ks*32768;
#pragma unroll
    for (int ni = 0; ni < 4; ++ni)
      fbx[ni] = *(const short8*)(bp + ni*128);
#pragma unroll
    for (int mi = 0; mi < 4; ++mi)
#pragma unroll
      for (int ni = 0; ni < 4; ++ni)
        acc[mi][ni] = __builtin_amdgcn_mfma_f32_16x16x32_bf16(
            fa[mi], fbx[ni], acc[mi][ni], 0, 0, 0);
  }

  // ---- epilogue 1: esum[row] += tanh(relu(c + bk[n])) * We_k[n] ----
  float esum[16];
#pragma unroll
  for (int q = 0; q < 16; ++q) esum[q] = 0.f;
#pragma unroll
  for (int ni = 0; ni < 4; ++ni) {
    const int n = w*64 + ni*16 + l16;
    const float bkv = bk[n];
    const float wev = We[D + n];
#pragma unroll
    for (int mi = 0; mi < 4; ++mi)
#pragma unroll
      for (int r = 0; r < 4; ++r) {
        float x = acc[mi][ni][r] + bkv;
        x = fmaxf(x, 0.f);
        float ex = __expf(2.f * x);
        float th = 1.f - 2.f/(ex + 1.f);
        esum[mi*4 + r] += th * wev;
      }
  }
#pragma unroll
  for (int dd = 1; dd < 16; dd <<= 1)
#pragma unroll
    for (int q = 0; q < 16; ++q)
      esum[q] += __shfl_xor(esum[q], dd, 64);

  if (l16 == 0) {
#pragma unroll
    for (int mi = 0; mi < 4; ++mi)
#pragma unroll
      for (int r = 0; r < 4; ++r)
        red2[(mi*16 + quad*4 + r)*16 + w] = esum[mi*4 + r];
  }
  __syncthreads();

  // ---- epilogue 2: chunk softmax stats (lanes 0..63 = 64 rows) ----
  if (tid < CROWS) {
    float e = 0.f;
#pragma unroll
    for (int wi = 0; wi < 16; ++wi) e += red2[tid*16 + wi];
    eraw[m0 + tid] = e;
    float mm = e;
#pragma unroll
    for (int dd = 1; dd < 64; dd <<= 1) mm = fmaxf(mm, __shfl_xor(mm, dd, 64));
    const float pv = __expf(e - mm);
    float ss = pv;
#pragma unroll
    for (int dd = 1; dd < 64; dd <<= 1) ss += __shfl_xor(ss, dd, 64);
    pfin[tid] = pv;
    if (tid == 0) { cmax[g] = mm; csum[g] = ss; }
  }
  __syncthreads();

  // ---- epilogue 3: partial_d = sum_s p_s * A_lds[s][d], d = 2*t, 2*t+1 ----
  if (tid < 512) {
    const int u    = tid >> 2;          // d/8
    const int joff = (tid & 3) * 2;     // d%8
    const short* ap = Al + (size_t)u*8 + joff;
    float a0 = 0.f, a1 = 0.f;
#pragma unroll 16
    for (int row = 0; row < CROWS; ++row) {
      const unsigned int bits = *(const unsigned int*)(ap + (size_t)row*1032);
      const float pv = pfin[row];
      const float lo = __builtin_bit_cast(float, bits << 16);
      const float hi = __builtin_bit_cast(float, bits & 0xffff0000u);
      a0 = fmaf(pv, lo, a0);
      a1 = fmaf(pv, hi, a1);
    }
    float2 o; o.x = a0; o.y = a1;
    *(float2*)(pattn + (size_t)g*D + 2*tid) = o;
  }
}

// ---------- Kernel 3: combine 32 chunk-partials per batch (tiny) ------------
// m_b = max_c m_c ; S_b = sum_c exp(m_c-m_b)*sumexp_c ;
// wts = exp(e-m_b)/S_b ; attn = (sum_c exp(m_c-m_b)*partial_c)/S_b.
__global__ __launch_bounds__(512) void attn_finalize(
    const float* __restrict__ eraw, const float* __restrict__ pattn,
    const float* __restrict__ cmax, const float* __restrict__ csum,
    float* __restrict__ wts, float* __restrict__ attn)
{
  const int b = blockIdx.x;
  const int t = threadIdx.x;
  __shared__ float scl[CPB];
  __shared__ float stats[2];

  if (t < CPB) {
    const float m = cmax[b*CPB + t];
    float mm = m;
#pragma unroll
    for (int dd = 1; dd < CPB; dd <<= 1) mm = fmaxf(mm, __shfl_xor(mm, dd, 64));
    const float e = __expf(m - mm);
    scl[t] = e;
    float s = e * csum[b*CPB + t];
#pragma unroll
    for (int dd = 1; dd < CPB; dd <<= 1) s += __shfl_xor(s, dd, 64);
    if (t == 0) { stats[0] = mm; stats[1] = 1.f / s; }
  }
  __syncthreads();
  const float m_b = stats[0];
  const float inv = stats[1];

  // weights: 2048 per batch, 4 per thread
#pragma unroll
  for (int j = 0; j < 4; ++j) {
    const int s = j*512 + t;
    wts[(size_t)b*SLEN + s] = __expf(eraw[(size_t)b*SLEN + s] - m_b) * inv;
  }

  // attn: 1024 cols, 2 per thread, combine CPB chunks
  float a0 = 0.f, a1 = 0.f;
#pragma unroll
  for (int c = 0; c < CPB; ++c) {
    const float sc = scl[c];
    const float* pp = pattn + ((size_t)(b*CPB + c))*D + t;
    a0 = fmaf(sc, pp[0],   a0);
    a1 = fmaf(sc, pp[512], a1);
  }
  attn[(size_t)b*D + t]       = a0 * inv;
  attn[(size_t)b*D + 512 + t] = a1 * inv;
}

extern "C" void kernel_launch(void* const* d_in, const int* in_sizes, int n_in,
                              void* d_out, int out_size, void* d_ws, size_t ws_size,
                              hipStream_t stream) {
  // inputs: 0=query 1=states 2=Wq 3=bq 4=Wk 5=bk 6=We 7=be
  // q-path terms are constant per softmax row -> cancel; dead code.
  const float* states = (const float*)d_in[1];
  const float* Wk     = (const float*)d_in[4];
  const float* bk     = (const float*)d_in[5];
  const float* We     = (const float*)d_in[6];
  float* out = (float*)d_out;            // [0:32768) attn_weights, [32768:49152) attn

  char* ws = (char*)d_ws;
  short* WkT   = (short*)ws;  ws += (size_t)D*D*sizeof(short);        // 2 MB
  float* eraw  = (float*)ws;  ws += (size_t)MROWS*sizeof(float);      // 128 KB
  float* pattn = (float*)ws;  ws += (size_t)NCHUNK*D*sizeof(float);   // 2 MB
  float* cmaxp = (float*)ws;  ws += (size_t)NCHUNK*sizeof(float);
  float* csump = (float*)ws;

  (void)in_sizes; (void)n_in; (void)out_size; (void)ws_size;

  wk_prep<<<128, 256, 0, stream>>>(Wk, WkT);
  energy_gemm<<<NCHUNK, 1024, 0, stream>>>(states, WkT, bk, We, eraw, pattn,
                                           cmaxp, csump);
  attn_finalize<<<BS, 512, 0, stream>>>(eraw, pattn, cmaxp, csump, out, out + MROWS);
}